// Round 12
// baseline (392.419 us; speedup 1.0000x reference)
//
#include <hip/hip_runtime.h>
#include <math.h>

#define NND 65536   // total nodes
#define NPER 512    // nodes per graph
#define NGR 128     // graphs (B)
#define DD 128      // feature dim
#define NED 524288  // edges

typedef __attribute__((ext_vector_type(8))) short short8;
typedef __attribute__((ext_vector_type(4))) float f32x4;

__device__ __forceinline__ unsigned short f2b(float f) {
  unsigned u = __float_as_uint(f);
  return (unsigned short)((u + 0x7FFFu + ((u >> 16) & 1u)) >> 16);
}
__device__ __forceinline__ float b2f(unsigned short h) {
  return __uint_as_float(((unsigned)h) << 16);
}

// ---------------- hist + weight prep (merged: independent work, no sync) ----------------
// blocks [0,2048): edge histogram. blocks [2048,2432): bf16 hi/lo weight split
// in MFMA-fragment order. counts pre-zeroed by hipMemsetAsync.

__global__ __launch_bounds__(256) void hist_prepw_kernel(
    const int* __restrict__ ei, int* __restrict__ counts,
    const float* __restrict__ wl0, const float* __restrict__ wr0,
    const float* __restrict__ wl1, const float* __restrict__ wr1,
    const float* __restrict__ wl2, const float* __restrict__ wr2,
    unsigned short* __restrict__ Whi, unsigned short* __restrict__ Wlo) {
  const int bid = blockIdx.x;
  if (bid < 2048) {
    int e = bid * 256 + threadIdx.x;
    atomicAdd(&counts[ei[NED + e]], 1);
    return;
  }
  const float* wls[3] = {wl0, wl1, wl2};
  const float* wrs[3] = {wr0, wr1, wr2};
  int e = (bid - 2048) * 256 + threadIdx.x;  // 3*32768
  int l = e >> 15;
  int o = e & 32767;
  int j = o & 7;
  int lane = (o >> 3) & 63;
  int nt = (o >> 9) & 7;
  int kc = o >> 12;
  int li = lane & 15, q = lane >> 4;
  int n = nt * 16 + li;
  int k = kc * 32 + q * 8 + j;
  const float* src = (k < 128) ? wls[l] : wrs[l];
  float v = src[n * DD + (k & 127)];
  unsigned short hi = f2b(v);
  float lo = v - b2f(hi);
  Whi[e] = hi;
  Wlo[e] = f2b(lo);
}

// ---------------- two-level parallel scan ----------------

__global__ __launch_bounds__(256) void scan1_kernel(const int* __restrict__ counts,
                                                    int* __restrict__ csum) {
  __shared__ int ws[4];
  const int b = blockIdx.x;
  const int t = threadIdx.x;
  const int4 v = ((const int4*)(counts + b * 1024))[t];
  int s = v.x + v.y + v.z + v.w;
#pragma unroll
  for (int o = 32; o > 0; o >>= 1) s += __shfl_down(s, o);
  if ((t & 63) == 0) ws[t >> 6] = s;
  __syncthreads();
  if (t == 0) csum[b] = ws[0] + ws[1] + ws[2] + ws[3];
}

__global__ __launch_bounds__(256) void scan2_kernel(const int* __restrict__ counts,
                                                    const int* __restrict__ csum,
                                                    int* __restrict__ off,
                                                    int* __restrict__ cursor) {
  __shared__ int s_part[256];
  __shared__ int s_base;
  const int b = blockIdx.x;
  const int t = threadIdx.x;
  const int4 v = ((const int4*)(counts + b * 1024))[t];
  const int s = v.x + v.y + v.z + v.w;
  s_part[t] = s;
  if (t < 64) {  // base = sum of preceding chunk sums
    int val = (t < b) ? csum[t] : 0;
#pragma unroll
    for (int o = 32; o > 0; o >>= 1) val += __shfl_down(val, o);
    if (t == 0) s_base = val;
  }
  __syncthreads();
  for (int d = 1; d < 256; d <<= 1) {  // inclusive Hillis-Steele over 256 partials
    int val = (t >= d) ? s_part[t - d] : 0;
    __syncthreads();
    s_part[t] += val;
    __syncthreads();
  }
  const int excl = s_base + ((t == 0) ? 0 : s_part[t - 1]);
  int4 o4;
  o4.x = excl;
  o4.y = excl + v.x;
  o4.z = o4.y + v.y;
  o4.w = o4.z + v.z;
  ((int4*)(off + b * 1024))[t] = o4;
  ((int4*)(cursor + b * 1024))[t] = o4;
  if (b == 0 && t == 0) off[NND] = NED;
}

__global__ __launch_bounds__(256) void scatter_kernel(const int* __restrict__ ei,
                                                      int* __restrict__ cursor,
                                                      int* __restrict__ ssrc) {
  int e = blockIdx.x * 256 + threadIdx.x;
  int dst = ei[NED + e];
  int pos = atomicAdd(&cursor[dst], 1);
  ssrc[pos] = ei[e];
}

// ---------------- mean aggregation: COLUMN-SPLIT two-pass gather ----------------
// R1 structure (4 dsts/wave, shared 64-edge window, half-split, 8 loads in
// flight) but each block handles ONE column-half (64 cols, float2/lane).
// Grid 8192 = 2 passes x 4096. Per-XCD read working set drops 4MB -> 2MB,
// fitting L2 alongside the (halved) mhi/mlo write stream, so the ~8x per-row
// reuse (avg degree) becomes L2 hits instead of L3 misses. Pass = bid>>12
// (temporal separation: pass-0 blocks dispatch before pass-1). Per-dst,
// per-column summation order identical to R1; passes write disjoint bytes.

template <int CM>
__global__ __launch_bounds__(256) void agg_kernel_t(const float* __restrict__ x,
                                                    const float2* __restrict__ tm,
                                                    const int* __restrict__ off,
                                                    const int* __restrict__ ssrc,
                                                    unsigned short* __restrict__ mhi,
                                                    unsigned short* __restrict__ mlo) {
  const int wave = threadIdx.x >> 6;
  const int lane = threadIdx.x & 63;
  const int half = lane >> 5;
  const int l = lane & 31;
  const int bid = blockIdx.x;
  const int ch = bid >> 12;        // column-half 0/1
  const int bid2 = bid & 4095;
  const int colbase = ch * 64;
  const int xcd = bid2 & 7;
  const int slot = bid2 >> 3;                // 0..511
  const int graph = xcd * 16 + (slot >> 5);  // 0..127
  const int within = slot & 31;              // 0..31
  const int d0 = graph * NPER + within * 16 + wave * 4;
  const float* xc = x + colbase + l * 2;     // this lane's 8B of the half

  int offv = 0;
  if (lane < 5) offv = off[d0 + lane];
  float deadv = 1.f;
  if (CM && lane < 4) deadv = tm[d0 + lane].x;
  const int b0 = __shfl(offv, 0);
  const int b1 = __shfl(offv, 1);
  const int b2 = __shfl(offv, 2);
  const int b3 = __shfl(offv, 3);
  const int e3 = __shfl(offv, 4);
  float dd[4];
  if (CM) {
    dd[0] = __shfl(deadv, 0);
    dd[1] = __shfl(deadv, 1);
    dd[2] = __shfl(deadv, 2);
    dd[3] = __shfl(deadv, 3);
  }
  const int begs[4] = {b0, b1, b2, b3};
  const int ends[4] = {b1, b2, b3, e3};

  float2 acc[4];
  int deg[4];
#pragma unroll
  for (int d = 0; d < 4; ++d) {
    acc[d] = make_float2(0.f, 0.f);
    deg[d] = 0;
  }

  for (int base = b0; base < e3; base += 64) {
    const int nwin = min(64, e3 - base);
    int sv = 0;
    float tv = 0.f;
    int live = 0;
    if (lane < nwin) {
      sv = ssrc[base + lane];
      if (CM) {
        const float2 mt = tm[sv];
        live = (mt.x != 0.f);
        tv = mt.y;
      }
    }
    unsigned long long bl;
    if (CM)
      bl = __ballot(live);
    else
      bl = (nwin == 64) ? ~0ull : ((1ull << nwin) - 1);

#pragma unroll
    for (int d = 0; d < 4; ++d) {
      if (CM && dd[d] == 0.f) continue;
      const int lo = max(begs[d], base);
      const int hi = min(ends[d], base + 64);
      if (lo >= hi) continue;
      const int j0 = lo - base;
      const int j1 = hi - base;
      const unsigned long long wm =
          (((j1 == 64) ? ~0ull : ((1ull << j1) - 1)) & ~((1ull << j0) - 1));
      deg[d] += (int)__popcll(bl & wm);
      int j = j0 + half;
      for (; j + 6 < j1; j += 8) {  // 4 half-row loads per half in flight
        const int s0 = __shfl(sv, j);
        const int s1 = __shfl(sv, j + 2);
        const int s2 = __shfl(sv, j + 4);
        const int s3 = __shfl(sv, j + 6);
        const float2 v0 = *(const float2*)(xc + (size_t)s0 * DD);
        const float2 v1 = *(const float2*)(xc + (size_t)s1 * DD);
        const float2 v2 = *(const float2*)(xc + (size_t)s2 * DD);
        const float2 v3 = *(const float2*)(xc + (size_t)s3 * DD);
        if (CM) {
          const float t0 = __shfl(tv, j), t1 = __shfl(tv, j + 2);
          const float t2 = __shfl(tv, j + 4), t3 = __shfl(tv, j + 6);
          acc[d].x += v0.x * t0 + v1.x * t1 + v2.x * t2 + v3.x * t3;
          acc[d].y += v0.y * t0 + v1.y * t1 + v2.y * t2 + v3.y * t3;
        } else {
          acc[d].x += v0.x + v1.x + v2.x + v3.x;
          acc[d].y += v0.y + v1.y + v2.y + v3.y;
        }
      }
      for (; j < j1; j += 2) {
        const int s = __shfl(sv, j);
        const float2 v = *(const float2*)(xc + (size_t)s * DD);
        if (CM) {
          const float t = __shfl(tv, j);
          acc[d].x += v.x * t;
          acc[d].y += v.y * t;
        } else {
          acc[d].x += v.x;
          acc[d].y += v.y;
        }
      }
    }
  }

#pragma unroll
  for (int d = 0; d < 4; ++d) {
    float2 a = acc[d];
    a.x += __shfl(a.x, lane ^ 32);
    a.y += __shfl(a.y, lane ^ 32);
    if (lane < 32) {
      const float inv = 1.f / (float)max(deg[d], 1);
      const float mx = a.x * inv;
      const float my = a.y * inv;
      ushort2 hv, lv;
      hv.x = f2b(mx); lv.x = f2b(mx - b2f(hv.x));
      hv.y = f2b(my); lv.y = f2b(my - b2f(hv.y));
      const size_t ad = (size_t)(d0 + d) * DD + colbase + l * 2;
      *(ushort2*)(mhi + ad) = hv;
      *(ushort2*)(mlo + ad) = lv;
    }
  }
}

// ---------------- MFMA bf16x3 GEMM + score epilogue (R1-exact) ----------------
// h = relu([mean | t.*x] @ W + bl). Mean arrives PRE-SPLIT (mhi/mlo from agg).
// LDS double-buffered: one barrier per kc.

#define GBM 64

template <int SCALE>
__global__ __launch_bounds__(256) void gemm_kernel_t(
    const unsigned short* __restrict__ Amh, const unsigned short* __restrict__ Aml,
    const float* __restrict__ Ax, const float2* __restrict__ tmp,
    const unsigned short* __restrict__ Whi, const unsigned short* __restrict__ Wlo,
    const float* __restrict__ bias, const float* __restrict__ pw,
    float* __restrict__ outp, float* __restrict__ sraw) {
  __shared__ short Ah[4096];  // 2 buffers x [m][lane][8]
  __shared__ short Al[4096];
  __shared__ float s_sp[4][GBM];
  const int tid = threadIdx.x;
  const int wv = tid >> 6;
  const int lane = tid & 63;
  const int q = lane >> 4;
  const int li = lane & 15;
  const int row0 = blockIdx.x * GBM;

  int sdst[2];
#pragma unroll
  for (int i = 0; i < 2; ++i) {
    const int id = tid + i * 256;
    const int r = id >> 3;
    const int kb = (id & 7) << 2;
    sdst[i] = ((r >> 4) * 64 + (kb >> 3) * 16 + (r & 15)) * 8 + (kb & 7);
  }

  f32x4 acc[4][2];
#pragma unroll
  for (int m = 0; m < 4; ++m)
#pragma unroll
    for (int n = 0; n < 2; ++n) acc[m][n] = (f32x4){0.f, 0.f, 0.f, 0.f};

  float4 pa[2];
  ushort4 pmh[2], pml[2];
  short8 pbh[2], pbl[2];

#define LOADA(KC)                                                                      \
  {                                                                                    \
    if ((KC) < 4) {                                                                    \
      const int cb = (KC)*32;                                                          \
      _Pragma("unroll") for (int i = 0; i < 2; ++i) {                                  \
        const int id = tid + i * 256;                                                  \
        const size_t ga = (size_t)(row0 + (id >> 3)) * DD + cb + ((id & 7) << 2);      \
        pmh[i] = *(const ushort4*)(Amh + ga);                                          \
        pml[i] = *(const ushort4*)(Aml + ga);                                          \
      }                                                                                \
    } else {                                                                           \
      const int cb = ((KC)&3) * 32;                                                    \
      _Pragma("unroll") for (int i = 0; i < 2; ++i) {                                  \
        const int id = tid + i * 256;                                                  \
        pa[i] = *(const float4*)(Ax + (size_t)(row0 + (id >> 3)) * DD + cb + ((id & 7) << 2)); \
        if (SCALE) {                                                                   \
          const float tt = tmp[row0 + (id >> 3)].y;                                    \
          pa[i].x *= tt; pa[i].y *= tt; pa[i].z *= tt; pa[i].w *= tt;                  \
        }                                                                              \
      }                                                                                \
    }                                                                                  \
  }
#define LOADB(KC)                                                                      \
  {                                                                                    \
    _Pragma("unroll") for (int n = 0; n < 2; ++n) {                                    \
      const int ga = (((KC)*8 + wv * 2 + n) * 64 + lane) * 8;                          \
      pbh[n] = *(const short8*)(Whi + ga);                                             \
      pbl[n] = *(const short8*)(Wlo + ga);                                             \
    }                                                                                  \
  }
#define STAGE(KC)                                                                      \
  {                                                                                    \
    short* Adh = Ah + ((KC)&1) * 2048;                                                 \
    short* Adl = Al + ((KC)&1) * 2048;                                                 \
    if ((KC) < 4) {                                                                    \
      _Pragma("unroll") for (int i = 0; i < 2; ++i) {                                  \
        *(ushort4*)(Adh + sdst[i]) = pmh[i];                                           \
        *(ushort4*)(Adl + sdst[i]) = pml[i];                                           \
      }                                                                                \
    } else {                                                                           \
      _Pragma("unroll") for (int i = 0; i < 2; ++i) {                                  \
        ushort4 hv, lv;                                                                \
        hv.x = f2b(pa[i].x); lv.x = f2b(pa[i].x - b2f(hv.x));                          \
        hv.y = f2b(pa[i].y); lv.y = f2b(pa[i].y - b2f(hv.y));                          \
        hv.z = f2b(pa[i].z); lv.z = f2b(pa[i].z - b2f(hv.z));                          \
        hv.w = f2b(pa[i].w); lv.w = f2b(pa[i].w - b2f(hv.w));                          \
        *(ushort4*)(Adh + sdst[i]) = hv;                                               \
        *(ushort4*)(Adl + sdst[i]) = lv;                                               \
      }                                                                                \
    }                                                                                  \
  }

  LOADA(0) LOADB(0)
  STAGE(0)   // buf 0
  LOADA(1)   // A(1) regs for next stage

#pragma unroll
  for (int kc = 0; kc < 8; ++kc) {
    short8 bh[2], bl[2];
    bh[0] = pbh[0]; bh[1] = pbh[1];
    bl[0] = pbl[0]; bl[1] = pbl[1];
    __syncthreads();  // STAGE(kc) (all waves) now visible
    short8 ah[4], al[4];
    const short* Ash = Ah + (kc & 1) * 2048;
    const short* Asl = Al + (kc & 1) * 2048;
#pragma unroll
    for (int m = 0; m < 4; ++m) {
      ah[m] = *(const short8*)(Ash + (m * 64 + lane) * 8);
      al[m] = *(const short8*)(Asl + (m * 64 + lane) * 8);
    }
    // stage kc+1 into the other buffer + prefetch kc+2 A / kc+1 B; overlaps MFMA
    switch (kc) {
      case 0: STAGE(1) LOADB(1) LOADA(2) break;
      case 1: STAGE(2) LOADB(2) LOADA(3) break;
      case 2: STAGE(3) LOADB(3) LOADA(4) break;
      case 3: STAGE(4) LOADB(4) LOADA(5) break;
      case 4: STAGE(5) LOADB(5) LOADA(6) break;
      case 5: STAGE(6) LOADB(6) LOADA(7) break;
      case 6: STAGE(7) LOADB(7) break;
      default: break;
    }
#pragma unroll
    for (int m = 0; m < 4; ++m)
#pragma unroll
      for (int n = 0; n < 2; ++n) {
        acc[m][n] = __builtin_amdgcn_mfma_f32_16x16x32_bf16(ah[m], bh[n], acc[m][n], 0, 0, 0);
        acc[m][n] = __builtin_amdgcn_mfma_f32_16x16x32_bf16(ah[m], bl[n], acc[m][n], 0, 0, 0);
        acc[m][n] = __builtin_amdgcn_mfma_f32_16x16x32_bf16(al[m], bh[n], acc[m][n], 0, 0, 0);
      }
  }
#undef LOADA
#undef LOADB
#undef STAGE

  // epilogue: bias+relu, store h (unscaled), fused score partials
  const int c0 = wv * 32 + li;
  const int c1 = wv * 32 + 16 + li;
  const float b0 = bias[c0], b1 = bias[c1];
  const float p0 = pw[c0], p1 = pw[c1];
  float sp[16];
#pragma unroll
  for (int m = 0; m < 4; ++m) {
#pragma unroll
    for (int i = 0; i < 4; ++i) {
      const int r = row0 + m * 16 + q * 4 + i;
      const float v0 = fmaxf(acc[m][0][i] + b0, 0.f);
      const float v1 = fmaxf(acc[m][1][i] + b1, 0.f);
      outp[(size_t)r * DD + c0] = v0;
      outp[(size_t)r * DD + c1] = v1;
      sp[m * 4 + i] = v0 * p0 + v1 * p1;
    }
  }
#pragma unroll
  for (int e = 0; e < 16; ++e) {
    sp[e] += __shfl_xor(sp[e], 1);
    sp[e] += __shfl_xor(sp[e], 2);
    sp[e] += __shfl_xor(sp[e], 4);
    sp[e] += __shfl_xor(sp[e], 8);
  }
  if (li == 0) {
#pragma unroll
    for (int e = 0; e < 16; ++e) s_sp[wv][(e >> 2) * 16 + q * 4 + (e & 3)] = sp[e];
  }
  __syncthreads();
  if (tid < GBM)
    sraw[row0 + tid] = s_sp[0][tid] + s_sp[1][tid] + s_sp[2][tid] + s_sp[3][tid];
}

// ---------------- topk + readout partials (h is read-only) ----------------
// FIRST=1 (layer 0): all nodes live -> no tmP read.

template <int FIRST>
__global__ __launch_bounds__(256) void pool_kernel_t(const float* __restrict__ h,
                                                     const float* __restrict__ sraw,
                                                     const float* __restrict__ pw,
                                                     const float2* __restrict__ tmP,
                                                     float2* __restrict__ tmN,
                                                     float* __restrict__ zp,
                                                     const int kk) {
  __shared__ float s_sc[NPER];
  __shared__ float s_t[128];
  __shared__ unsigned char s_sel[128];
  __shared__ int s_rk[256];
  __shared__ float4 red4[512];
  __shared__ float s_norm;
  const int b = blockIdx.x;
  const int g = b >> 2;
  const int q = b & 3;
  const int tid = threadIdx.x;
  const int lane = tid & 63;

  if (tid < 64) {
    const float v0 = pw[lane], v1 = pw[lane + 64];
    float p = v0 * v0 + v1 * v1;
#pragma unroll
    for (int o = 32; o > 0; o >>= 1) p += __shfl_down(p, o);
    if (lane == 0) s_norm = 1.f / (sqrtf(p) + 1e-16f);
  }
  __syncthreads();
  const float inv_norm = s_norm;
#pragma unroll
  for (int i = 0; i < 2; ++i) {
    const int n = tid + i * 256;
    const int node = g * NPER + n;
    if (FIRST)
      s_sc[n] = sraw[node] * inv_norm;
    else
      s_sc[n] = (tmP[node].x != 0.f) ? sraw[node] * inv_norm : -INFINITY;
  }
  __syncthreads();

  {
    const int n = q * 128 + (tid & 127);
    const int jb = (tid >> 7) * 256;
    const float s = s_sc[n];
    int rank = 0;
    for (int j = jb; j < jb + 256; ++j) {
      const float sj = s_sc[j];
      rank += (sj > s || (sj == s && j < n)) ? 1 : 0;
    }
    s_rk[tid] = rank;
  }
  __syncthreads();
  if (tid < 128) {
    const int n = q * 128 + tid;
    const int rank = s_rk[tid] + s_rk[tid + 128];
    const int sel = (rank < kk) ? 1 : 0;
    const float s = s_sc[n];
    const float t = sel ? tanhf(s) : 0.f;
    tmN[g * NPER + n] = make_float2(sel ? 1.f : 0.f, t);
    s_sel[tid] = (unsigned char)sel;
    s_t[tid] = t;
  }
  __syncthreads();

  const int c = tid & 31;
  const int r = tid >> 5;
  float4 pmax = make_float4(-INFINITY, -INFINITY, -INFINITY, -INFINITY);
  float4 psum = make_float4(0.f, 0.f, 0.f, 0.f);
  const size_t nbase = (size_t)g * NPER + q * 128;
  const float4* h4 = (const float4*)h;
  for (int i = 0; i < 16; ++i) {
    const int nl = r + 8 * i;
    if (s_sel[nl]) {
      float4 v = h4[(nbase + nl) * 32 + c];
      const float t = s_t[nl];
      v.x *= t; v.y *= t; v.z *= t; v.w *= t;
      pmax.x = fmaxf(pmax.x, v.x);
      pmax.y = fmaxf(pmax.y, v.y);
      pmax.z = fmaxf(pmax.z, v.z);
      pmax.w = fmaxf(pmax.w, v.w);
      psum.x += v.x; psum.y += v.y; psum.z += v.z; psum.w += v.w;
    }
  }
  red4[r * 32 + c] = pmax;
  red4[256 + r * 32 + c] = psum;
  __syncthreads();
  if (tid < 32) {
    float4 m = red4[tid];
    float4 sm = red4[256 + tid];
#pragma unroll
    for (int rr = 1; rr < 8; ++rr) {
      const float4 a = red4[rr * 32 + tid];
      const float4 s2 = red4[256 + rr * 32 + tid];
      m.x = fmaxf(m.x, a.x); m.y = fmaxf(m.y, a.y);
      m.z = fmaxf(m.z, a.z); m.w = fmaxf(m.w, a.w);
      sm.x += s2.x; sm.y += s2.y; sm.z += s2.z; sm.w += s2.w;
    }
    *(float4*)(zp + (size_t)b * 256 + tid * 4) = m;
    *(float4*)(zp + (size_t)b * 256 + 128 + tid * 4) = sm;
  }
}

// ---------------- MLP head (reduces 4 partials/graph/layer) ----------------

__global__ __launch_bounds__(128) void mlp_kernel(const float* __restrict__ zpart,
                                                  const float* __restrict__ w1,
                                                  const float* __restrict__ b1,
                                                  const float* __restrict__ w2,
                                                  const float* __restrict__ b2,
                                                  const float* __restrict__ w3,
                                                  const float* __restrict__ b3,
                                                  float* __restrict__ out,
                                                  const float ik0, const float ik1,
                                                  const float ik2) {
  __shared__ float z[256];
  __shared__ float h1[128];
  __shared__ float h2[64];
  const int g = blockIdx.x;
  const int t = threadIdx.x;
  const float iks[3] = {ik0, ik1, ik2};
  float zmax = 0.f, zmean = 0.f;
#pragma unroll
  for (int l = 0; l < 3; ++l) {
    const float* zp = zpart + ((size_t)l * 512 + g * 4) * 256;
    zmax += fmaxf(fmaxf(zp[t], zp[256 + t]), fmaxf(zp[512 + t], zp[768 + t]));
    zmean += (zp[128 + t] + zp[384 + t] + zp[640 + t] + zp[896 + t]) * iks[l];
  }
  z[t] = zmax;
  z[128 + t] = zmean;
  __syncthreads();
  float a = b1[t];
  for (int k = 0; k < 256; ++k) a = fmaf(z[k], w1[t * 256 + k], a);
  h1[t] = fmaxf(a, 0.f);
  __syncthreads();
  if (t < 64) {
    float a2 = b2[t];
    for (int k = 0; k < 128; ++k) a2 = fmaf(h1[k], w2[t * 128 + k], a2);
    h2[t] = fmaxf(a2, 0.f);
  }
  __syncthreads();
  if (t == 0) {
    float a3 = b3[0];
    for (int k = 0; k < 64; ++k) a3 = fmaf(h2[k], w3[k], a3);
    out[g] = 1.f / (1.f + expf(-a3));
  }
}

// ---------------- launch ----------------

extern "C" void kernel_launch(void* const* d_in, const int* in_sizes, int n_in,
                              void* d_out, int out_size, void* d_ws, size_t ws_size,
                              hipStream_t stream) {
  (void)in_sizes; (void)n_in; (void)out_size; (void)ws_size;
  const float* x_in = (const float*)d_in[0];
  const int* ei = (const int*)d_in[1];
  const float* wl[3] = {(const float*)d_in[2], (const float*)d_in[6], (const float*)d_in[10]};
  const float* cbl[3] = {(const float*)d_in[3], (const float*)d_in[7], (const float*)d_in[11]};
  const float* wr[3] = {(const float*)d_in[4], (const float*)d_in[8], (const float*)d_in[12]};
  const float* pw[3] = {(const float*)d_in[5], (const float*)d_in[9], (const float*)d_in[13]};
  const float* l1w = (const float*)d_in[14];
  const float* l1b = (const float*)d_in[15];
  const float* l2w = (const float*)d_in[16];
  const float* l2b = (const float*)d_in[17];
  const float* l3w = (const float*)d_in[18];
  const float* l3b = (const float*)d_in[19];
  float* out = (float*)d_out;

  char* w = (char*)d_ws;
  int* counts = (int*)(w + 0 * (1 << 20));  // zeroed by memset; dead after scan2
  int* off = (int*)(w + 1 * (1 << 20));
  int* csum = (int*)(w + 1 * (1 << 20) + (1 << 19));  // 64 ints, inside off's MB
  int* cursor = (int*)(w + 2 * (1 << 20));  // dead after scatter
  float* sraw = (float*)(w + 2 * (1 << 20));  // reuses cursor (256KB)
  float2* tmA = (float2*)(w + 3 * (1 << 20));              // 512KB (no init needed)
  float2* tmB = (float2*)(w + 3 * (1 << 20) + (1 << 19));  // 512KB
  float* zpart = (float*)(w + 4 * (1 << 20));              // 1.5MB (4..5.5MB)
  unsigned short* Whi = (unsigned short*)(w + 5 * (1 << 20) + (1 << 19));      // 192KB
  unsigned short* Wlo = (unsigned short*)(w + 5 * (1 << 20) + 3 * (1 << 18));  // 192KB
  int* ssrc = (int*)(w + 6 * (1 << 20));               // 2MB
  unsigned short* mhi = (unsigned short*)(w + (size_t)8 * (1 << 20));   // 16MB
  unsigned short* mlo = (unsigned short*)(w + (size_t)24 * (1 << 20));  // 16MB
  float* hA = (float*)(w + (size_t)40 * (1 << 20));    // 32MB
  float* hB = (float*)(w + (size_t)72 * (1 << 20));    // 32MB (total 104MB)

  hipMemsetAsync(counts, 0, NND * sizeof(int), stream);
  hist_prepw_kernel<<<2432, 256, 0, stream>>>(ei, counts, wl[0], wr[0], wl[1], wr[1],
                                              wl[2], wr[2], Whi, Wlo);
  scan1_kernel<<<64, 256, 0, stream>>>(counts, csum);
  scan2_kernel<<<64, 256, 0, stream>>>(counts, csum, off, cursor);
  scatter_kernel<<<NED / 256, 256, 0, stream>>>(ei, cursor, ssrc);

  const int ks[3] = {410, 328, 263};
  const float* xl = x_in;
  float* houts[3] = {hA, hB, hA};
  float2* tprev[3] = {tmA, tmB, tmA};
  float2* tnext[3] = {tmB, tmA, tmB};
  for (int l = 0; l < 3; ++l) {
    float* hout = houts[l];
    if (l == 0) {
      agg_kernel_t<0><<<8192, 256, 0, stream>>>(xl, tprev[l], off, ssrc, mhi, mlo);
      gemm_kernel_t<0><<<NND / GBM, 256, 0, stream>>>(mhi, mlo, xl, tprev[l],
                                                      Whi + (size_t)l * 32768,
                                                      Wlo + (size_t)l * 32768, cbl[l], pw[l],
                                                      hout, sraw);
      pool_kernel_t<1><<<NGR * 4, 256, 0, stream>>>(hout, sraw, pw[l], tprev[l], tnext[l],
                                                    zpart + (size_t)l * 512 * 256, ks[l]);
    } else {
      agg_kernel_t<1><<<8192, 256, 0, stream>>>(xl, tprev[l], off, ssrc, mhi, mlo);
      gemm_kernel_t<1><<<NND / GBM, 256, 0, stream>>>(mhi, mlo, xl, tprev[l],
                                                      Whi + (size_t)l * 32768,
                                                      Wlo + (size_t)l * 32768, cbl[l], pw[l],
                                                      hout, sraw);
      pool_kernel_t<0><<<NGR * 4, 256, 0, stream>>>(hout, sraw, pw[l], tprev[l], tnext[l],
                                                    zpart + (size_t)l * 512 * 256, ks[l]);
    }
    xl = hout;
  }
  mlp_kernel<<<NGR, 128, 0, stream>>>(zpart, l1w, l1b, l2w, l2b, l3w, l3b, out,
                                      1.f / 410.f, 1.f / 328.f, 1.f / 263.f);
}

// Round 13
// 360.570 us; speedup vs baseline: 1.0883x; 1.0883x over previous
//
#include <hip/hip_runtime.h>
#include <math.h>

#define NND 65536   // total nodes
#define NPER 512    // nodes per graph
#define NGR 128     // graphs (B)
#define DD 128      // feature dim
#define NED 524288  // edges

typedef __attribute__((ext_vector_type(8))) short short8;
typedef __attribute__((ext_vector_type(4))) float f32x4;

__device__ __forceinline__ unsigned short f2b(float f) {
  unsigned u = __float_as_uint(f);
  return (unsigned short)((u + 0x7FFFu + ((u >> 16) & 1u)) >> 16);
}
__device__ __forceinline__ float b2f(unsigned short h) {
  return __uint_as_float(((unsigned)h) << 16);
}

// ---------------- hist + weight prep (merged: independent work, no sync) ----------------
// blocks [0,2048): edge histogram. blocks [2048,2432): bf16 hi/lo weight split
// in MFMA-fragment order. counts pre-zeroed by hipMemsetAsync.

__global__ __launch_bounds__(256) void hist_prepw_kernel(
    const int* __restrict__ ei, int* __restrict__ counts,
    const float* __restrict__ wl0, const float* __restrict__ wr0,
    const float* __restrict__ wl1, const float* __restrict__ wr1,
    const float* __restrict__ wl2, const float* __restrict__ wr2,
    unsigned short* __restrict__ Whi, unsigned short* __restrict__ Wlo) {
  const int bid = blockIdx.x;
  if (bid < 2048) {
    int e = bid * 256 + threadIdx.x;
    atomicAdd(&counts[ei[NED + e]], 1);
    return;
  }
  const float* wls[3] = {wl0, wl1, wl2};
  const float* wrs[3] = {wr0, wr1, wr2};
  int e = (bid - 2048) * 256 + threadIdx.x;  // 3*32768
  int l = e >> 15;
  int o = e & 32767;
  int j = o & 7;
  int lane = (o >> 3) & 63;
  int nt = (o >> 9) & 7;
  int kc = o >> 12;
  int li = lane & 15, q = lane >> 4;
  int n = nt * 16 + li;
  int k = kc * 32 + q * 8 + j;
  const float* src = (k < 128) ? wls[l] : wrs[l];
  float v = src[n * DD + (k & 127)];
  unsigned short hi = f2b(v);
  float lo = v - b2f(hi);
  Whi[e] = hi;
  Wlo[e] = f2b(lo);
}

// ---------------- two-level parallel scan ----------------

__global__ __launch_bounds__(256) void scan1_kernel(const int* __restrict__ counts,
                                                    int* __restrict__ csum) {
  __shared__ int ws[4];
  const int b = blockIdx.x;
  const int t = threadIdx.x;
  const int4 v = ((const int4*)(counts + b * 1024))[t];
  int s = v.x + v.y + v.z + v.w;
#pragma unroll
  for (int o = 32; o > 0; o >>= 1) s += __shfl_down(s, o);
  if ((t & 63) == 0) ws[t >> 6] = s;
  __syncthreads();
  if (t == 0) csum[b] = ws[0] + ws[1] + ws[2] + ws[3];
}

__global__ __launch_bounds__(256) void scan2_kernel(const int* __restrict__ counts,
                                                    const int* __restrict__ csum,
                                                    int* __restrict__ off,
                                                    int* __restrict__ cursor) {
  __shared__ int s_part[256];
  __shared__ int s_base;
  const int b = blockIdx.x;
  const int t = threadIdx.x;
  const int4 v = ((const int4*)(counts + b * 1024))[t];
  const int s = v.x + v.y + v.z + v.w;
  s_part[t] = s;
  if (t < 64) {  // base = sum of preceding chunk sums
    int val = (t < b) ? csum[t] : 0;
#pragma unroll
    for (int o = 32; o > 0; o >>= 1) val += __shfl_down(val, o);
    if (t == 0) s_base = val;
  }
  __syncthreads();
  for (int d = 1; d < 256; d <<= 1) {  // inclusive Hillis-Steele over 256 partials
    int val = (t >= d) ? s_part[t - d] : 0;
    __syncthreads();
    s_part[t] += val;
    __syncthreads();
  }
  const int excl = s_base + ((t == 0) ? 0 : s_part[t - 1]);
  int4 o4;
  o4.x = excl;
  o4.y = excl + v.x;
  o4.z = o4.y + v.y;
  o4.w = o4.z + v.z;
  ((int4*)(off + b * 1024))[t] = o4;
  ((int4*)(cursor + b * 1024))[t] = o4;
  if (b == 0 && t == 0) off[NND] = NED;
}

__global__ __launch_bounds__(256) void scatter_kernel(const int* __restrict__ ei,
                                                      int* __restrict__ cursor,
                                                      int* __restrict__ ssrc) {
  int e = blockIdx.x * 256 + threadIdx.x;
  int dst = ei[NED + e];
  int pos = atomicAdd(&cursor[dst], 1);
  ssrc[pos] = ei[e];
}

// ---------------- mean aggregation: 4 dsts/wave, shared prologue (R1-exact) ----------------
// The measured-best agg (session minimum 361.99us). Six structural variants
// (LDS-staged, window-precomputed, hybrid, mask-fma, fused, column-split) all
// measured worse. R12 counters (col-split): VALUBusy 45%, HBM 14%, conflicts 0
// -> agg is per-edge-issue/latency-bound, not BW-bound; this structure has the
// lowest per-edge overhead found.

template <int CM>
__global__ __launch_bounds__(256) void agg_kernel_t(const float* __restrict__ x,
                                                    const float2* __restrict__ tm,
                                                    const int* __restrict__ off,
                                                    const int* __restrict__ ssrc,
                                                    unsigned short* __restrict__ mhi,
                                                    unsigned short* __restrict__ mlo) {
  const int wave = threadIdx.x >> 6;
  const int lane = threadIdx.x & 63;
  const int half = lane >> 5;
  const int l = lane & 31;
  // 4096 blocks = 8 xcd * 16 graphs * 32 slots; 16 dsts/block, 4/wave
  const int bid = blockIdx.x;
  const int xcd = bid & 7;
  const int slot = bid >> 3;                 // 0..511
  const int graph = xcd * 16 + (slot >> 5);  // 0..127
  const int within = slot & 31;              // 0..31
  const int d0 = graph * NPER + within * 16 + wave * 4;

  int offv = 0;
  if (lane < 5) offv = off[d0 + lane];
  float deadv = 1.f;
  if (CM && lane < 4) deadv = tm[d0 + lane].x;
  const int b0 = __shfl(offv, 0);
  const int b1 = __shfl(offv, 1);
  const int b2 = __shfl(offv, 2);
  const int b3 = __shfl(offv, 3);
  const int e3 = __shfl(offv, 4);
  float dd[4];
  if (CM) {
    dd[0] = __shfl(deadv, 0);
    dd[1] = __shfl(deadv, 1);
    dd[2] = __shfl(deadv, 2);
    dd[3] = __shfl(deadv, 3);
  }
  const int begs[4] = {b0, b1, b2, b3};
  const int ends[4] = {b1, b2, b3, e3};

  float4 acc[4];
  int deg[4];
#pragma unroll
  for (int d = 0; d < 4; ++d) {
    acc[d] = make_float4(0.f, 0.f, 0.f, 0.f);
    deg[d] = 0;
  }

  for (int base = b0; base < e3; base += 64) {
    const int nwin = min(64, e3 - base);
    int sv = 0;
    float tv = 0.f;
    int live = 0;
    if (lane < nwin) {
      sv = ssrc[base + lane];
      if (CM) {
        const float2 mt = tm[sv];
        live = (mt.x != 0.f);
        tv = mt.y;
      }
    }
    unsigned long long bl;
    if (CM)
      bl = __ballot(live);
    else
      bl = (nwin == 64) ? ~0ull : ((1ull << nwin) - 1);

#pragma unroll
    for (int d = 0; d < 4; ++d) {
      if (CM && dd[d] == 0.f) continue;
      const int lo = max(begs[d], base);
      const int hi = min(ends[d], base + 64);
      if (lo >= hi) continue;
      const int j0 = lo - base;
      const int j1 = hi - base;
      const unsigned long long wm =
          (((j1 == 64) ? ~0ull : ((1ull << j1) - 1)) & ~((1ull << j0) - 1));
      deg[d] += (int)__popcll(bl & wm);
      int j = j0 + half;
      for (; j + 6 < j1; j += 8) {  // 4 edges per half in flight
        const int s0 = __shfl(sv, j);
        const int s1 = __shfl(sv, j + 2);
        const int s2 = __shfl(sv, j + 4);
        const int s3 = __shfl(sv, j + 6);
        const float4 v0 = *(const float4*)(x + (size_t)s0 * DD + l * 4);
        const float4 v1 = *(const float4*)(x + (size_t)s1 * DD + l * 4);
        const float4 v2 = *(const float4*)(x + (size_t)s2 * DD + l * 4);
        const float4 v3 = *(const float4*)(x + (size_t)s3 * DD + l * 4);
        if (CM) {
          const float t0 = __shfl(tv, j), t1 = __shfl(tv, j + 2);
          const float t2 = __shfl(tv, j + 4), t3 = __shfl(tv, j + 6);
          acc[d].x += v0.x * t0 + v1.x * t1 + v2.x * t2 + v3.x * t3;
          acc[d].y += v0.y * t0 + v1.y * t1 + v2.y * t2 + v3.y * t3;
          acc[d].z += v0.z * t0 + v1.z * t1 + v2.z * t2 + v3.z * t3;
          acc[d].w += v0.w * t0 + v1.w * t1 + v2.w * t2 + v3.w * t3;
        } else {
          acc[d].x += v0.x + v1.x + v2.x + v3.x;
          acc[d].y += v0.y + v1.y + v2.y + v3.y;
          acc[d].z += v0.z + v1.z + v2.z + v3.z;
          acc[d].w += v0.w + v1.w + v2.w + v3.w;
        }
      }
      for (; j < j1; j += 2) {
        const int s = __shfl(sv, j);
        const float4 v = *(const float4*)(x + (size_t)s * DD + l * 4);
        if (CM) {
          const float t = __shfl(tv, j);
          acc[d].x += v.x * t;
          acc[d].y += v.y * t;
          acc[d].z += v.z * t;
          acc[d].w += v.w * t;
        } else {
          acc[d].x += v.x;
          acc[d].y += v.y;
          acc[d].z += v.z;
          acc[d].w += v.w;
        }
      }
    }
  }

#pragma unroll
  for (int d = 0; d < 4; ++d) {
    float4 a = acc[d];
    a.x += __shfl(a.x, lane ^ 32);
    a.y += __shfl(a.y, lane ^ 32);
    a.z += __shfl(a.z, lane ^ 32);
    a.w += __shfl(a.w, lane ^ 32);
    if (lane < 32) {
      const float inv = 1.f / (float)max(deg[d], 1);
      float4 m;
      m.x = a.x * inv;
      m.y = a.y * inv;
      m.z = a.z * inv;
      m.w = a.w * inv;
      ushort4 hv, lv;
      hv.x = f2b(m.x); lv.x = f2b(m.x - b2f(hv.x));
      hv.y = f2b(m.y); lv.y = f2b(m.y - b2f(hv.y));
      hv.z = f2b(m.z); lv.z = f2b(m.z - b2f(hv.z));
      hv.w = f2b(m.w); lv.w = f2b(m.w - b2f(hv.w));
      const size_t ad = (size_t)(d0 + d) * DD + l * 4;
      *(ushort4*)(mhi + ad) = hv;
      *(ushort4*)(mlo + ad) = lv;
    }
  }
}

// ---------------- MFMA bf16x3 GEMM + score epilogue (R1-exact) ----------------
// h = relu([mean | t.*x] @ W + bl). Mean arrives PRE-SPLIT (mhi/mlo from agg).
// LDS double-buffered: one barrier per kc.

#define GBM 64

template <int SCALE>
__global__ __launch_bounds__(256) void gemm_kernel_t(
    const unsigned short* __restrict__ Amh, const unsigned short* __restrict__ Aml,
    const float* __restrict__ Ax, const float2* __restrict__ tmp,
    const unsigned short* __restrict__ Whi, const unsigned short* __restrict__ Wlo,
    const float* __restrict__ bias, const float* __restrict__ pw,
    float* __restrict__ outp, float* __restrict__ sraw) {
  __shared__ short Ah[4096];  // 2 buffers x [m][lane][8]
  __shared__ short Al[4096];
  __shared__ float s_sp[4][GBM];
  const int tid = threadIdx.x;
  const int wv = tid >> 6;
  const int lane = tid & 63;
  const int q = lane >> 4;
  const int li = lane & 15;
  const int row0 = blockIdx.x * GBM;

  int sdst[2];
#pragma unroll
  for (int i = 0; i < 2; ++i) {
    const int id = tid + i * 256;
    const int r = id >> 3;
    const int kb = (id & 7) << 2;
    sdst[i] = ((r >> 4) * 64 + (kb >> 3) * 16 + (r & 15)) * 8 + (kb & 7);
  }

  f32x4 acc[4][2];
#pragma unroll
  for (int m = 0; m < 4; ++m)
#pragma unroll
    for (int n = 0; n < 2; ++n) acc[m][n] = (f32x4){0.f, 0.f, 0.f, 0.f};

  float4 pa[2];
  ushort4 pmh[2], pml[2];
  short8 pbh[2], pbl[2];

#define LOADA(KC)                                                                      \
  {                                                                                    \
    if ((KC) < 4) {                                                                    \
      const int cb = (KC)*32;                                                          \
      _Pragma("unroll") for (int i = 0; i < 2; ++i) {                                  \
        const int id = tid + i * 256;                                                  \
        const size_t ga = (size_t)(row0 + (id >> 3)) * DD + cb + ((id & 7) << 2);      \
        pmh[i] = *(const ushort4*)(Amh + ga);                                          \
        pml[i] = *(const ushort4*)(Aml + ga);                                          \
      }                                                                                \
    } else {                                                                           \
      const int cb = ((KC)&3) * 32;                                                    \
      _Pragma("unroll") for (int i = 0; i < 2; ++i) {                                  \
        const int id = tid + i * 256;                                                  \
        pa[i] = *(const float4*)(Ax + (size_t)(row0 + (id >> 3)) * DD + cb + ((id & 7) << 2)); \
        if (SCALE) {                                                                   \
          const float tt = tmp[row0 + (id >> 3)].y;                                    \
          pa[i].x *= tt; pa[i].y *= tt; pa[i].z *= tt; pa[i].w *= tt;                  \
        }                                                                              \
      }                                                                                \
    }                                                                                  \
  }
#define LOADB(KC)                                                                      \
  {                                                                                    \
    _Pragma("unroll") for (int n = 0; n < 2; ++n) {                                    \
      const int ga = (((KC)*8 + wv * 2 + n) * 64 + lane) * 8;                          \
      pbh[n] = *(const short8*)(Whi + ga);                                             \
      pbl[n] = *(const short8*)(Wlo + ga);                                             \
    }                                                                                  \
  }
#define STAGE(KC)                                                                      \
  {                                                                                    \
    short* Adh = Ah + ((KC)&1) * 2048;                                                 \
    short* Adl = Al + ((KC)&1) * 2048;                                                 \
    if ((KC) < 4) {                                                                    \
      _Pragma("unroll") for (int i = 0; i < 2; ++i) {                                  \
        *(ushort4*)(Adh + sdst[i]) = pmh[i];                                           \
        *(ushort4*)(Adl + sdst[i]) = pml[i];                                           \
      }                                                                                \
    } else {                                                                           \
      _Pragma("unroll") for (int i = 0; i < 2; ++i) {                                  \
        ushort4 hv, lv;                                                                \
        hv.x = f2b(pa[i].x); lv.x = f2b(pa[i].x - b2f(hv.x));                          \
        hv.y = f2b(pa[i].y); lv.y = f2b(pa[i].y - b2f(hv.y));                          \
        hv.z = f2b(pa[i].z); lv.z = f2b(pa[i].z - b2f(hv.z));                          \
        hv.w = f2b(pa[i].w); lv.w = f2b(pa[i].w - b2f(hv.w));                          \
        *(ushort4*)(Adh + sdst[i]) = hv;                                               \
        *(ushort4*)(Adl + sdst[i]) = lv;                                               \
      }                                                                                \
    }                                                                                  \
  }

  LOADA(0) LOADB(0)
  STAGE(0)   // buf 0
  LOADA(1)   // A(1) regs for next stage

#pragma unroll
  for (int kc = 0; kc < 8; ++kc) {
    short8 bh[2], bl[2];
    bh[0] = pbh[0]; bh[1] = pbh[1];
    bl[0] = pbl[0]; bl[1] = pbl[1];
    __syncthreads();  // STAGE(kc) (all waves) now visible
    short8 ah[4], al[4];
    const short* Ash = Ah + (kc & 1) * 2048;
    const short* Asl = Al + (kc & 1) * 2048;
#pragma unroll
    for (int m = 0; m < 4; ++m) {
      ah[m] = *(const short8*)(Ash + (m * 64 + lane) * 8);
      al[m] = *(const short8*)(Asl + (m * 64 + lane) * 8);
    }
    // stage kc+1 into the other buffer + prefetch kc+2 A / kc+1 B; overlaps MFMA
    switch (kc) {
      case 0: STAGE(1) LOADB(1) LOADA(2) break;
      case 1: STAGE(2) LOADB(2) LOADA(3) break;
      case 2: STAGE(3) LOADB(3) LOADA(4) break;
      case 3: STAGE(4) LOADB(4) LOADA(5) break;
      case 4: STAGE(5) LOADB(5) LOADA(6) break;
      case 5: STAGE(6) LOADB(6) LOADA(7) break;
      case 6: STAGE(7) LOADB(7) break;
      default: break;
    }
#pragma unroll
    for (int m = 0; m < 4; ++m)
#pragma unroll
      for (int n = 0; n < 2; ++n) {
        acc[m][n] = __builtin_amdgcn_mfma_f32_16x16x32_bf16(ah[m], bh[n], acc[m][n], 0, 0, 0);
        acc[m][n] = __builtin_amdgcn_mfma_f32_16x16x32_bf16(ah[m], bl[n], acc[m][n], 0, 0, 0);
        acc[m][n] = __builtin_amdgcn_mfma_f32_16x16x32_bf16(al[m], bh[n], acc[m][n], 0, 0, 0);
      }
  }
#undef LOADA
#undef LOADB
#undef STAGE

  // epilogue: bias+relu, store h (unscaled), fused score partials
  const int c0 = wv * 32 + li;
  const int c1 = wv * 32 + 16 + li;
  const float b0 = bias[c0], b1 = bias[c1];
  const float p0 = pw[c0], p1 = pw[c1];
  float sp[16];
#pragma unroll
  for (int m = 0; m < 4; ++m) {
#pragma unroll
    for (int i = 0; i < 4; ++i) {
      const int r = row0 + m * 16 + q * 4 + i;
      const float v0 = fmaxf(acc[m][0][i] + b0, 0.f);
      const float v1 = fmaxf(acc[m][1][i] + b1, 0.f);
      outp[(size_t)r * DD + c0] = v0;
      outp[(size_t)r * DD + c1] = v1;
      sp[m * 4 + i] = v0 * p0 + v1 * p1;
    }
  }
#pragma unroll
  for (int e = 0; e < 16; ++e) {
    sp[e] += __shfl_xor(sp[e], 1);
    sp[e] += __shfl_xor(sp[e], 2);
    sp[e] += __shfl_xor(sp[e], 4);
    sp[e] += __shfl_xor(sp[e], 8);
  }
  if (li == 0) {
#pragma unroll
    for (int e = 0; e < 16; ++e) s_sp[wv][(e >> 2) * 16 + q * 4 + (e & 3)] = sp[e];
  }
  __syncthreads();
  if (tid < GBM)
    sraw[row0 + tid] = s_sp[0][tid] + s_sp[1][tid] + s_sp[2][tid] + s_sp[3][tid];
}

// ---------------- topk + readout partials (h is read-only) ----------------
// FIRST=1 (layer 0): all nodes live -> no tmP read.

template <int FIRST>
__global__ __launch_bounds__(256) void pool_kernel_t(const float* __restrict__ h,
                                                     const float* __restrict__ sraw,
                                                     const float* __restrict__ pw,
                                                     const float2* __restrict__ tmP,
                                                     float2* __restrict__ tmN,
                                                     float* __restrict__ zp,
                                                     const int kk) {
  __shared__ float s_sc[NPER];
  __shared__ float s_t[128];
  __shared__ unsigned char s_sel[128];
  __shared__ int s_rk[256];
  __shared__ float4 red4[512];
  __shared__ float s_norm;
  const int b = blockIdx.x;
  const int g = b >> 2;
  const int q = b & 3;
  const int tid = threadIdx.x;
  const int lane = tid & 63;

  if (tid < 64) {
    const float v0 = pw[lane], v1 = pw[lane + 64];
    float p = v0 * v0 + v1 * v1;
#pragma unroll
    for (int o = 32; o > 0; o >>= 1) p += __shfl_down(p, o);
    if (lane == 0) s_norm = 1.f / (sqrtf(p) + 1e-16f);
  }
  __syncthreads();
  const float inv_norm = s_norm;
#pragma unroll
  for (int i = 0; i < 2; ++i) {
    const int n = tid + i * 256;
    const int node = g * NPER + n;
    if (FIRST)
      s_sc[n] = sraw[node] * inv_norm;
    else
      s_sc[n] = (tmP[node].x != 0.f) ? sraw[node] * inv_norm : -INFINITY;
  }
  __syncthreads();

  {
    const int n = q * 128 + (tid & 127);
    const int jb = (tid >> 7) * 256;
    const float s = s_sc[n];
    int rank = 0;
    for (int j = jb; j < jb + 256; ++j) {
      const float sj = s_sc[j];
      rank += (sj > s || (sj == s && j < n)) ? 1 : 0;
    }
    s_rk[tid] = rank;
  }
  __syncthreads();
  if (tid < 128) {
    const int n = q * 128 + tid;
    const int rank = s_rk[tid] + s_rk[tid + 128];
    const int sel = (rank < kk) ? 1 : 0;
    const float s = s_sc[n];
    const float t = sel ? tanhf(s) : 0.f;
    tmN[g * NPER + n] = make_float2(sel ? 1.f : 0.f, t);
    s_sel[tid] = (unsigned char)sel;
    s_t[tid] = t;
  }
  __syncthreads();

  const int c = tid & 31;
  const int r = tid >> 5;
  float4 pmax = make_float4(-INFINITY, -INFINITY, -INFINITY, -INFINITY);
  float4 psum = make_float4(0.f, 0.f, 0.f, 0.f);
  const size_t nbase = (size_t)g * NPER + q * 128;
  const float4* h4 = (const float4*)h;
  for (int i = 0; i < 16; ++i) {
    const int nl = r + 8 * i;
    if (s_sel[nl]) {
      float4 v = h4[(nbase + nl) * 32 + c];
      const float t = s_t[nl];
      v.x *= t; v.y *= t; v.z *= t; v.w *= t;
      pmax.x = fmaxf(pmax.x, v.x);
      pmax.y = fmaxf(pmax.y, v.y);
      pmax.z = fmaxf(pmax.z, v.z);
      pmax.w = fmaxf(pmax.w, v.w);
      psum.x += v.x; psum.y += v.y; psum.z += v.z; psum.w += v.w;
    }
  }
  red4[r * 32 + c] = pmax;
  red4[256 + r * 32 + c] = psum;
  __syncthreads();
  if (tid < 32) {
    float4 m = red4[tid];
    float4 sm = red4[256 + tid];
#pragma unroll
    for (int rr = 1; rr < 8; ++rr) {
      const float4 a = red4[rr * 32 + tid];
      const float4 s2 = red4[256 + rr * 32 + tid];
      m.x = fmaxf(m.x, a.x); m.y = fmaxf(m.y, a.y);
      m.z = fmaxf(m.z, a.z); m.w = fmaxf(m.w, a.w);
      sm.x += s2.x; sm.y += s2.y; sm.z += s2.z; sm.w += s2.w;
    }
    *(float4*)(zp + (size_t)b * 256 + tid * 4) = m;
    *(float4*)(zp + (size_t)b * 256 + 128 + tid * 4) = sm;
  }
}

// ---------------- MLP head (reduces 4 partials/graph/layer) ----------------

__global__ __launch_bounds__(128) void mlp_kernel(const float* __restrict__ zpart,
                                                  const float* __restrict__ w1,
                                                  const float* __restrict__ b1,
                                                  const float* __restrict__ w2,
                                                  const float* __restrict__ b2,
                                                  const float* __restrict__ w3,
                                                  const float* __restrict__ b3,
                                                  float* __restrict__ out,
                                                  const float ik0, const float ik1,
                                                  const float ik2) {
  __shared__ float z[256];
  __shared__ float h1[128];
  __shared__ float h2[64];
  const int g = blockIdx.x;
  const int t = threadIdx.x;
  const float iks[3] = {ik0, ik1, ik2};
  float zmax = 0.f, zmean = 0.f;
#pragma unroll
  for (int l = 0; l < 3; ++l) {
    const float* zp = zpart + ((size_t)l * 512 + g * 4) * 256;
    zmax += fmaxf(fmaxf(zp[t], zp[256 + t]), fmaxf(zp[512 + t], zp[768 + t]));
    zmean += (zp[128 + t] + zp[384 + t] + zp[640 + t] + zp[896 + t]) * iks[l];
  }
  z[t] = zmax;
  z[128 + t] = zmean;
  __syncthreads();
  float a = b1[t];
  for (int k = 0; k < 256; ++k) a = fmaf(z[k], w1[t * 256 + k], a);
  h1[t] = fmaxf(a, 0.f);
  __syncthreads();
  if (t < 64) {
    float a2 = b2[t];
    for (int k = 0; k < 128; ++k) a2 = fmaf(h1[k], w2[t * 128 + k], a2);
    h2[t] = fmaxf(a2, 0.f);
  }
  __syncthreads();
  if (t == 0) {
    float a3 = b3[0];
    for (int k = 0; k < 64; ++k) a3 = fmaf(h2[k], w3[k], a3);
    out[g] = 1.f / (1.f + expf(-a3));
  }
}

// ---------------- launch ----------------

extern "C" void kernel_launch(void* const* d_in, const int* in_sizes, int n_in,
                              void* d_out, int out_size, void* d_ws, size_t ws_size,
                              hipStream_t stream) {
  (void)in_sizes; (void)n_in; (void)out_size; (void)ws_size;
  const float* x_in = (const float*)d_in[0];
  const int* ei = (const int*)d_in[1];
  const float* wl[3] = {(const float*)d_in[2], (const float*)d_in[6], (const float*)d_in[10]};
  const float* cbl[3] = {(const float*)d_in[3], (const float*)d_in[7], (const float*)d_in[11]};
  const float* wr[3] = {(const float*)d_in[4], (const float*)d_in[8], (const float*)d_in[12]};
  const float* pw[3] = {(const float*)d_in[5], (const float*)d_in[9], (const float*)d_in[13]};
  const float* l1w = (const float*)d_in[14];
  const float* l1b = (const float*)d_in[15];
  const float* l2w = (const float*)d_in[16];
  const float* l2b = (const float*)d_in[17];
  const float* l3w = (const float*)d_in[18];
  const float* l3b = (const float*)d_in[19];
  float* out = (float*)d_out;

  char* w = (char*)d_ws;
  int* counts = (int*)(w + 0 * (1 << 20));  // zeroed by memset; dead after scan2
  int* off = (int*)(w + 1 * (1 << 20));
  int* csum = (int*)(w + 1 * (1 << 20) + (1 << 19));  // 64 ints, inside off's MB
  int* cursor = (int*)(w + 2 * (1 << 20));  // dead after scatter
  float* sraw = (float*)(w + 2 * (1 << 20));  // reuses cursor (256KB)
  float2* tmA = (float2*)(w + 3 * (1 << 20));              // 512KB (no init needed)
  float2* tmB = (float2*)(w + 3 * (1 << 20) + (1 << 19));  // 512KB
  float* zpart = (float*)(w + 4 * (1 << 20));              // 1.5MB (4..5.5MB)
  unsigned short* Whi = (unsigned short*)(w + 5 * (1 << 20) + (1 << 19));      // 192KB
  unsigned short* Wlo = (unsigned short*)(w + 5 * (1 << 20) + 3 * (1 << 18));  // 192KB
  int* ssrc = (int*)(w + 6 * (1 << 20));               // 2MB
  unsigned short* mhi = (unsigned short*)(w + (size_t)8 * (1 << 20));   // 16MB
  unsigned short* mlo = (unsigned short*)(w + (size_t)24 * (1 << 20));  // 16MB
  float* hA = (float*)(w + (size_t)40 * (1 << 20));    // 32MB
  float* hB = (float*)(w + (size_t)72 * (1 << 20));    // 32MB (total 104MB)

  hipMemsetAsync(counts, 0, NND * sizeof(int), stream);
  hist_prepw_kernel<<<2432, 256, 0, stream>>>(ei, counts, wl[0], wr[0], wl[1], wr[1],
                                              wl[2], wr[2], Whi, Wlo);
  scan1_kernel<<<64, 256, 0, stream>>>(counts, csum);
  scan2_kernel<<<64, 256, 0, stream>>>(counts, csum, off, cursor);
  scatter_kernel<<<NED / 256, 256, 0, stream>>>(ei, cursor, ssrc);

  const int ks[3] = {410, 328, 263};
  const float* xl = x_in;
  float* houts[3] = {hA, hB, hA};
  float2* tprev[3] = {tmA, tmB, tmA};
  float2* tnext[3] = {tmB, tmA, tmB};
  for (int l = 0; l < 3; ++l) {
    float* hout = houts[l];
    if (l == 0) {
      agg_kernel_t<0><<<4096, 256, 0, stream>>>(xl, tprev[l], off, ssrc, mhi, mlo);
      gemm_kernel_t<0><<<NND / GBM, 256, 0, stream>>>(mhi, mlo, xl, tprev[l],
                                                      Whi + (size_t)l * 32768,
                                                      Wlo + (size_t)l * 32768, cbl[l], pw[l],
                                                      hout, sraw);
      pool_kernel_t<1><<<NGR * 4, 256, 0, stream>>>(hout, sraw, pw[l], tprev[l], tnext[l],
                                                    zpart + (size_t)l * 512 * 256, ks[l]);
    } else {
      agg_kernel_t<1><<<4096, 256, 0, stream>>>(xl, tprev[l], off, ssrc, mhi, mlo);
      gemm_kernel_t<1><<<NND / GBM, 256, 0, stream>>>(mhi, mlo, xl, tprev[l],
                                                      Whi + (size_t)l * 32768,
                                                      Wlo + (size_t)l * 32768, cbl[l], pw[l],
                                                      hout, sraw);
      pool_kernel_t<0><<<NGR * 4, 256, 0, stream>>>(hout, sraw, pw[l], tprev[l], tnext[l],
                                                    zpart + (size_t)l * 512 * 256, ks[l]);
    }
    xl = hout;
  }
  mlp_kernel<<<NGR, 128, 0, stream>>>(zpart, l1w, l1b, l2w, l2b, l3w, l3b, out,
                                      1.f / 410.f, 1.f / 328.f, 1.f / 263.f);
}